// Round 2
// baseline (2506.569 us; speedup 1.0000x reference)
//
#include <hip/hip_runtime.h>
#include <hip/hip_bf16.h>

typedef unsigned short u16;
typedef __attribute__((ext_vector_type(8))) short short8;
typedef __attribute__((ext_vector_type(4))) float floatx4;

__device__ __forceinline__ u16 f2bf(float x) {
  unsigned u = __float_as_uint(x);
  u += 0x7fffu + ((u >> 16) & 1u);           // round-to-nearest-even to bf16
  return (u16)(u >> 16);
}
__device__ __forceinline__ float bf2f(u16 u) {
  return __uint_as_float(((unsigned)u) << 16);
}
__device__ __forceinline__ float sigm(float x) {
  return 1.0f / (1.0f + __expf(-x));
}

// ---------------- prep kernels ----------------

// x1,x2: (B=4, T=8, 128, 32, 32) fp32 -> Xs: [t][b][256][1024] bf16 hi/lo
__global__ __launch_bounds__(256) void xsplit_kernel(
    const float* __restrict__ x1, const float* __restrict__ x2,
    u16* __restrict__ Xh, u16* __restrict__ Xl)
{
  int i = blockIdx.x * 256 + threadIdx.x;   // 2^23 total
  int pix = i & 1023;
  int c2  = (i >> 10) & 255;
  int b   = (i >> 18) & 3;
  int t   = i >> 20;
  const float* src = (c2 < 128) ? x1 : x2;
  int c = c2 & 127;
  float v = src[((((size_t)b * 8 + t) * 128 + c) << 10) + pix];
  u16 h = f2bf(v);
  Xh[i] = h;
  Xl[i] = f2bf(v - bf2f(h));
}

// W: (512, CIN, 3, 3) fp32 -> Wr: [n=512][k = (ky*3+kx)*CIN + ci] bf16 hi/lo
__global__ __launch_bounds__(256) void wsplit_kernel(
    const float* __restrict__ W, u16* __restrict__ Wh, u16* __restrict__ Wl, int CIN)
{
  int K = CIN * 9;
  int i = blockIdx.x * 256 + threadIdx.x;   // grid sized exactly 512*K/256
  int n = i / K;
  int k = i - n * K;
  int e9 = k / CIN;
  int ci = k - e9 * CIN;
  float v = W[((size_t)n * CIN + ci) * 9 + e9];
  u16 h = f2bf(v);
  Wh[i] = h;
  Wl[i] = f2bf(v - bf2f(h));
}

__global__ __launch_bounds__(256) void init_state(
    float* __restrict__ c1, float* __restrict__ c2, float* __restrict__ c3,
    u16* __restrict__ h1h, u16* __restrict__ h1l,
    u16* __restrict__ h2h, u16* __restrict__ h2l,
    u16* __restrict__ h3h, u16* __restrict__ h3l)
{
  int i = blockIdx.x * 256 + threadIdx.x;   // 524288
  c1[i] = 0.f; c2[i] = 0.f; c3[i] = 0.f;
  h1h[i] = 0; h1l[i] = 0; h2h[i] = 0; h2l[i] = 0; h3h[i] = 0; h3l[i] = 0;
}

// ---------------- conv as GEMM ----------------
// z[n][m] = sum_k A[m][k] * W[n][k],  m=(b,y,x) in [0,4096), n in [0,512),
// k = (ky*3+kx)*CIN + ci, A[m][k] = in[b][ci][y+ky-1][x+kx-1] (0 outside).
// A-source split across two tensors: ci<CA from A1 ([b][CA][1024]), else A2.
// hi/lo bf16 split: acc += Ah*Wh + Ah*Wl + Al*Wh  (fp32-grade precision).
// Block: 256 thr = 4 waves; tile 64m x 64n; wave tile 32x32 (2x2 frags 16x16x32).
__global__ __launch_bounds__(256) void conv_gemm(
    const u16* __restrict__ A1h, const u16* __restrict__ A1l, int CA,
    const u16* __restrict__ A2h, const u16* __restrict__ A2l, int CB,
    const u16* __restrict__ Wh, const u16* __restrict__ Wl,
    float* __restrict__ z)
{
  const int CIN = CA + CB;
  const int K = CIN * 9;

  __shared__ __align__(16) char smem[20480];
  u16 (*Ah)[40] = reinterpret_cast<u16(*)[40]>(smem);          // 64 x 40 bf16, pad->80B stride
  u16 (*Al)[40] = reinterpret_cast<u16(*)[40]>(smem + 5120);
  u16 (*Bh)[40] = reinterpret_cast<u16(*)[40]>(smem + 10240);  // [n][k] layout
  u16 (*Bl)[40] = reinterpret_cast<u16(*)[40]>(smem + 15360);

  int tid = threadIdx.x;
  int bx  = blockIdx.x;
  int nt = bx & 7;        // 8 n-tiles
  int mt = bx >> 3;       // 64 m-tiles
  int m0 = mt * 64;
  int b  = m0 >> 10;
  int y0 = (m0 & 1023) >> 5;   // tile covers rows y0, y0+1, all 32 x

  // staging roles
  int mm  = tid & 63;          // A: pixel within tile
  int kk0 = tid >> 6;          // A: k-lane 0..3 (strided by 4)
  int bn  = tid >> 2;          // B: row (n) 0..63
  int bk  = (tid & 3) * 8;     // B: k offset (16B chunks)

  int lane = tid & 63;
  int wid  = tid >> 6;
  int wm = wid >> 1, wn = wid & 1;
  int fr = lane & 15, kq = lane >> 4;

  floatx4 acc[2][2];
  #pragma unroll
  for (int i2 = 0; i2 < 2; ++i2)
    #pragma unroll
    for (int j2 = 0; j2 < 2; ++j2)
      acc[i2][j2] = (floatx4)0.0f;

  int myy = y0 + (mm >> 5);
  int mxx = mm & 31;

  const size_t wrow = (size_t)(nt * 64 + bn) * K + bk;

  for (int e9 = 0; e9 < 9; ++e9) {
    int dy = e9 / 3 - 1;
    int dx = e9 - (dy + 1) * 3 - 1;
    int yy = myy + dy;
    int xx = mxx + dx;
    bool valid = ((unsigned)yy < 32u) & ((unsigned)xx < 32u);
    int sp = valid ? (yy * 32 + xx) : 0;      // clamped: safe dummy load
    int nCC = CIN >> 5;
    for (int cc = 0; cc < nCC; ++cc) {
      int ci0 = cc << 5;
      // ---- A stage (im2col gather, 8 elems/thread per array) ----
      const u16* sh; const u16* sl; int cb, Cs;
      if (ci0 < CA) { sh = A1h; sl = A1l; cb = ci0;      Cs = CA; }
      else          { sh = A2h; sl = A2l; cb = ci0 - CA; Cs = CB; }
      size_t abase = ((size_t)(b * Cs + cb + kk0) << 10) + sp;
      #pragma unroll
      for (int i = 0; i < 8; ++i) {
        u16 vh = sh[abase + ((size_t)i << 12)];   // +4 channels * 1024
        u16 vl = sl[abase + ((size_t)i << 12)];
        if (!valid) { vh = 0; vl = 0; }
        Ah[mm][kk0 + 4 * i] = vh;
        Al[mm][kk0 + 4 * i] = vl;
      }
      // ---- B stage (one 16B load + write per thread per array) ----
      size_t wb = wrow + (size_t)(e9 * CIN + ci0);
      *reinterpret_cast<short8*>(&Bh[bn][bk]) = *reinterpret_cast<const short8*>(&Wh[wb]);
      *reinterpret_cast<short8*>(&Bl[bn][bk]) = *reinterpret_cast<const short8*>(&Wl[wb]);
      __syncthreads();

      // ---- fragments + 12 MFMA (3 split-products x 2x2 frags) ----
      short8 va_h[2], va_l[2], vb_h[2], vb_l[2];
      #pragma unroll
      for (int f = 0; f < 2; ++f) {
        va_h[f] = *reinterpret_cast<const short8*>(&Ah[wm * 32 + f * 16 + fr][kq * 8]);
        va_l[f] = *reinterpret_cast<const short8*>(&Al[wm * 32 + f * 16 + fr][kq * 8]);
        vb_h[f] = *reinterpret_cast<const short8*>(&Bh[wn * 32 + f * 16 + fr][kq * 8]);
        vb_l[f] = *reinterpret_cast<const short8*>(&Bl[wn * 32 + f * 16 + fr][kq * 8]);
      }
      #pragma unroll
      for (int mf = 0; mf < 2; ++mf)
        #pragma unroll
        for (int nf = 0; nf < 2; ++nf) {
          acc[mf][nf] = __builtin_amdgcn_mfma_f32_16x16x32_bf16(va_h[mf], vb_h[nf], acc[mf][nf], 0, 0, 0);
          acc[mf][nf] = __builtin_amdgcn_mfma_f32_16x16x32_bf16(va_h[mf], vb_l[nf], acc[mf][nf], 0, 0, 0);
          acc[mf][nf] = __builtin_amdgcn_mfma_f32_16x16x32_bf16(va_l[mf], vb_h[nf], acc[mf][nf], 0, 0, 0);
        }
      __syncthreads();
    }
  }

  // ---- epilogue: per-wave 32x32 transpose in LDS -> coalesced [n][m] store ----
  float* tr = reinterpret_cast<float*>(smem + wid * 4096);   // 32n x 32m fp32
  #pragma unroll
  for (int mf = 0; mf < 2; ++mf)
    #pragma unroll
    for (int nf = 0; nf < 2; ++nf)
      #pragma unroll
      for (int r = 0; r < 4; ++r)
        tr[(nf * 16 + fr) * 32 + mf * 16 + kq * 4 + r] = acc[mf][nf][r];
  int n_base = nt * 64 + wn * 32;
  int m_base = m0 + wm * 32;
  #pragma unroll
  for (int it = 0; it < 4; ++it) {
    int row = it * 8 + (lane >> 3);
    int mq  = (lane & 7) * 4;
    floatx4 v = *reinterpret_cast<const floatx4*>(&tr[row * 32 + mq]);
    *reinterpret_cast<floatx4*>(&z[(size_t)(n_base + row) * 4096 + m_base + mq]) = v;
  }
}

// ---------------- fused gates + state update ----------------
// z: [512][4096] (n-major). c,h: [b][128][1024]. Writes h as bf16 hi/lo.
__global__ __launch_bounds__(256) void gate_kernel(
    const float* __restrict__ z, const float* __restrict__ bias,
    float* __restrict__ c, u16* __restrict__ hh, u16* __restrict__ hl,
    float* __restrict__ hout)
{
  int g = blockIdx.x * 256 + threadIdx.x;   // 524288 = (b, oc, pix)
  int pix = g & 1023;
  int oc  = (g >> 10) & 127;
  int b   = g >> 17;
  size_t m = ((size_t)b << 10) + pix;
  float zi = z[(size_t)(oc      ) * 4096 + m] + bias[oc];
  float zf = z[(size_t)(oc + 128) * 4096 + m] + bias[oc + 128];
  float zo = z[(size_t)(oc + 256) * 4096 + m] + bias[oc + 256];
  float zg = z[(size_t)(oc + 384) * 4096 + m] + bias[oc + 384];
  float cv = c[g];
  float cn = sigm(zf) * cv + sigm(zi) * tanhf(zg);
  float hn = sigm(zo) * tanhf(cn);
  c[g] = cn;
  u16 hb = f2bf(hn);
  hh[g] = hb;
  hl[g] = f2bf(hn - bf2f(hb));
  if (hout) hout[g] = hn;
}

extern "C" void kernel_launch(void* const* d_in, const int* in_sizes, int n_in,
                              void* d_out, int out_size, void* d_ws, size_t ws_size,
                              hipStream_t stream)
{
  const float* x1 = (const float*)d_in[0];
  const float* x2 = (const float*)d_in[1];
  const float* W1 = (const float*)d_in[2];
  const float* b1 = (const float*)d_in[3];
  const float* W2 = (const float*)d_in[4];
  const float* b2 = (const float*)d_in[5];
  const float* W3 = (const float*)d_in[6];
  const float* b3 = (const float*)d_in[7];
  float* out = (float*)d_out;

  char* ws = (char*)d_ws;
  size_t off = 0;
  auto alloc = [&](size_t bytes) {
    char* p = ws + off;
    off += (bytes + 255) & ~(size_t)255;
    return p;
  };
  u16*   Xh  = (u16*)  alloc(16777216);   // [8][4][256][1024] bf16
  u16*   Xl  = (u16*)  alloc(16777216);
  u16*   W1h = (u16*)  alloc(3538944);    // [512][3456]
  u16*   W1l = (u16*)  alloc(3538944);
  u16*   W2h = (u16*)  alloc(2359296);    // [512][2304]
  u16*   W2l = (u16*)  alloc(2359296);
  u16*   W3h = (u16*)  alloc(2359296);
  u16*   W3l = (u16*)  alloc(2359296);
  u16*   h1h = (u16*)  alloc(1048576);    // [4][128][1024] bf16
  u16*   h1l = (u16*)  alloc(1048576);
  u16*   h2h = (u16*)  alloc(1048576);
  u16*   h2l = (u16*)  alloc(1048576);
  u16*   h3h = (u16*)  alloc(1048576);
  u16*   h3l = (u16*)  alloc(1048576);
  float* c1  = (float*)alloc(2097152);    // [4][128][1024] fp32
  float* c2  = (float*)alloc(2097152);
  float* c3  = (float*)alloc(2097152);
  float* z   = (float*)alloc(8388608);    // [512][4096] fp32
  if (off > ws_size) return;              // clean fail if workspace too small

  xsplit_kernel<<<32768, 256, 0, stream>>>(x1, x2, Xh, Xl);
  wsplit_kernel<<<6912, 256, 0, stream>>>(W1, W1h, W1l, 384);
  wsplit_kernel<<<4608, 256, 0, stream>>>(W2, W2h, W2l, 256);
  wsplit_kernel<<<4608, 256, 0, stream>>>(W3, W3h, W3l, 256);
  init_state<<<2048, 256, 0, stream>>>(c1, c2, c3, h1h, h1l, h2h, h2l, h3h, h3l);

  for (int t = 0; t < 8; ++t) {
    const u16* Xth = Xh + (size_t)t * 1048576;
    const u16* Xtl = Xl + (size_t)t * 1048576;
    // layer 1: [x_t (256ch), h1 (128ch)] -> gates -> h1,c1
    conv_gemm<<<512, 256, 0, stream>>>(Xth, Xtl, 256, h1h, h1l, 128, W1h, W1l, z);
    gate_kernel<<<2048, 256, 0, stream>>>(z, b1, c1, h1h, h1l, nullptr);
    // layer 2: [h1, h2]
    conv_gemm<<<512, 256, 0, stream>>>(h1h, h1l, 128, h2h, h2l, 128, W2h, W2l, z);
    gate_kernel<<<2048, 256, 0, stream>>>(z, b2, c2, h2h, h2l, nullptr);
    // layer 3: [h2, h3]
    conv_gemm<<<512, 256, 0, stream>>>(h2h, h2l, 128, h3h, h3l, 128, W3h, W3l, z);
    gate_kernel<<<2048, 256, 0, stream>>>(z, b3, c3, h3h, h3l, (t == 7) ? out : nullptr);
  }
}